// Round 5
// baseline (267.192 us; speedup 1.0000x reference)
//
#include <hip/hip_runtime.h>
#include <hip/hip_bf16.h>
#include <cmath>
#include <stdint.h>

#define B_ 8
#define T_ 2048
#define C_ 1024
#define HS_ 64
#define NS 8           // key splits per q-tile
#define LP 72          // attn LDS row stride in shorts

typedef __attribute__((ext_vector_type(8))) short short8;    // 8 bf16 (4 VGPRs) - MFMA A/B frag
typedef __attribute__((ext_vector_type(4))) float floatx4;   // MFMA C/D frag

__device__ inline unsigned short f2bf(float f) {
    union { float f; unsigned u; } v; v.f = f;
    unsigned r = v.u + 0x7FFF + ((v.u >> 16) & 1);   // RNE
    return (unsigned short)(r >> 16);
}
__device__ inline unsigned pk2bf(float a, float b) {   // -> v_cvt_pk_bf16_f32
    union { __hip_bfloat162 h; unsigned u; } v;
    v.h = __float22bfloat162_rn(float2{a, b});
    return v.u;
}
__device__ inline float bf2f(unsigned short u) {
    union { unsigned u; float f; } w; w.u = ((unsigned)u) << 16; return w.f;
}
// async global->LDS, 16B per lane; LDS dest = wave-uniform base + lane*16
__device__ inline void gl2lds16(const void* g, void* l) {
    __builtin_amdgcn_global_load_lds(
        (const __attribute__((address_space(1))) unsigned int*)g,
        (__attribute__((address_space(3))) unsigned int*)l,
        16, 0, 0);
}

// ---------------------------------------------------------------------------
// Kernel 1: W [C x HS] fp32  ->  W^T [HS x C] bf16  (3 matrices)
// ---------------------------------------------------------------------------
__global__ __launch_bounds__(256) void prep_wt(const float* __restrict__ Wq,
                                               const float* __restrict__ Wk,
                                               const float* __restrict__ Wv,
                                               unsigned short* __restrict__ wt) {
    int p = blockIdx.x >> 4;
    int chunk = blockIdx.x & 15;
    const float* W = (p == 0) ? Wq : (p == 1) ? Wk : Wv;
    unsigned short* WT = wt + p * (C_ * HS_);
    int base = chunk * 4096;
    for (int i = threadIdx.x; i < 4096; i += 256) {
        int idx = base + i;
        int k = idx >> 6, n = idx & 63;
        WT[n * C_ + k] = f2bf(W[idx]);
    }
}

// ---------------------------------------------------------------------------
// Kernel 2: projections. X [16384x1024] fp32 @ W [1024x64] -> bf16 [16384x64]
// grid = 768 (3 proj x 256 row tiles of 64), block = 256 (4 waves).
// Staging via async global_load_lds (width=16) — compiler cannot sink it and
// loads queue on vmcnt with no VGPR round trip (round-4 bottleneck).
// X staged RAW fp32 (cvt at fragment-read; VALU is idle). XOR block swizzle
// on the global source index makes fragment ds_read_b128 conflict-free.
// ---------------------------------------------------------------------------
__global__ __launch_bounds__(256) void proj_kernel(
    const float* __restrict__ qv, const float* __restrict__ kv, const float* __restrict__ vv,
    const unsigned short* __restrict__ wt,
    unsigned short* __restrict__ qb, unsigned short* __restrict__ kb, unsigned short* __restrict__ vb)
{
    __shared__ __align__(16) float Xl[64 * 64];            // 16 KB: [row][blk^ (row&15)] fp32, 16 blocks/row
    __shared__ __align__(16) unsigned short Wl[64 * 64];   // 8 KB:  [n]  [blk^ (n&7)]   bf16, 8 blocks/row

    const int bid  = blockIdx.x;
    const int p    = bid >> 8;
    const int tile = bid & 255;
    const float* X = (p == 0) ? qv : (p == 1) ? kv : vv;
    const unsigned short* WT = wt + p * (C_ * HS_);
    unsigned short* Ob = (p == 0) ? qb : (p == 1) ? kb : vb;
    const float oscale = (p == 0) ? 0.125f : 1.0f;

    const int tid = threadIdx.x;
    const int wave = tid >> 6, lane = tid & 63, quad = lane >> 4, l16 = lane & 15;
    const long rowbase = (long)tile * 64;
    const float* Xbase = X + rowbase * C_;

    // staging geometry (per gl2lds instr: 64 lanes x 16B = 1KB)
    const int xrow_l = lane >> 4, xblk = lane & 15;   // X: 4 rows/instr
    const int wrow_l = lane >> 3, wblk = lane & 7;    // W: 8 rows/instr

    floatx4 acc[4] = { {0,0,0,0},{0,0,0,0},{0,0,0,0},{0,0,0,0} };

    for (int c = 0; c < 16; ++c) {
        const int kc = c * 64;
        // X: wave issues instrs i = wave*4..+3, rows 4i..4i+3
        #pragma unroll
        for (int ii = 0; ii < 4; ++ii) {
            int i = wave * 4 + ii;
            int row = i * 4 + xrow_l;
            const float* src = Xbase + (long)row * C_ + kc + ((xblk ^ (row & 15)) * 4);
            gl2lds16(src, &Xl[i * 256]);
        }
        // W: wave issues instrs j = wave*2..+1, rows 8j..8j+7
        #pragma unroll
        for (int jj = 0; jj < 2; ++jj) {
            int j = wave * 2 + jj;
            int row = j * 8 + wrow_l;
            const unsigned short* src = WT + row * C_ + kc + ((wblk ^ (row & 7)) * 8);
            gl2lds16(src, &Wl[j * 512]);
        }
        __syncthreads();   // drains vmcnt -> tiles resident in LDS

        // compute: 2 k-steps of 32, 4 n-tiles (pure LDS + MFMA + cvt)
        #pragma unroll
        for (int ks = 0; ks < 2; ++ks) {
            const int xrow = wave * 16 + l16;
            int lb = (ks * 8 + 2 * quad) ^ l16;          // low-col block (swizzle s = row&15 = l16)
            const float* xr = &Xl[xrow * 64];
            floatx4 flo = *(const floatx4*)(xr + lb * 4);
            floatx4 fhi = *(const floatx4*)(xr + (lb ^ 1) * 4);
            union { short8 s8; unsigned u[4]; } af;
            af.u[0] = pk2bf(flo[0], flo[1]); af.u[1] = pk2bf(flo[2], flo[3]);
            af.u[2] = pk2bf(fhi[0], fhi[1]); af.u[3] = pk2bf(fhi[2], fhi[3]);
            #pragma unroll
            for (int nt = 0; nt < 4; ++nt) {
                int wrow = nt * 16 + l16;
                int wb = (ks * 4 + quad) ^ (l16 & 7);
                short8 bf = *(const short8*)&Wl[wrow * 64 + wb * 8];
                acc[nt] = __builtin_amdgcn_mfma_f32_16x16x32_bf16(af.s8, bf, acc[nt], 0, 0, 0);
            }
        }
        __syncthreads();   // protect LDS reuse
    }

    // C-layout: row = quad*4+r (X row), col = nt*16+l16 (h)
    #pragma unroll
    for (int nt = 0; nt < 4; ++nt)
        #pragma unroll
        for (int r = 0; r < 4; ++r) {
            long row = rowbase + wave * 16 + quad * 4 + r;
            Ob[row * HS_ + nt * 16 + l16] = f2bf(acc[nt][r] * oscale);
        }
}

// ---------------------------------------------------------------------------
// Kernel 3a: flash attention partials with key-split.
// grid = 8b x 32qt x NS splits = 2048 WGs, block = 256 (4 waves x 16 q-rows).
// ---------------------------------------------------------------------------
__global__ __launch_bounds__(256) void attn_partial(
    const unsigned short* __restrict__ qb, const unsigned short* __restrict__ kb,
    const unsigned short* __restrict__ vb, const int* __restrict__ mask,
    unsigned short* __restrict__ Opart, float* __restrict__ Mpart, float* __restrict__ Lpart)
{
    const int s  = blockIdx.x & (NS - 1);
    const int bq = blockIdx.x >> 3;          // b*32 + qt
    const int qt = bq & 31;
    const int b  = bq >> 5;
    if (s > qt) return;                       // empty split; combine skips it

    __shared__ unsigned short Klds[64 * LP];      // K chunk [key][feat]
    __shared__ unsigned short Vt[64 * LP];        // V chunk transposed [feat][key]
    __shared__ unsigned short Plds[4][16 * LP];   // per-wave P scratch [qrow][key]

    const int tid = threadIdx.x;
    const int wave = tid >> 6, lane = tid & 63, quad = lane >> 4, l16 = lane & 15;

    // Q fragments (A-operand: m = l16, k = quad*8+j); scale folded in.
    const int qrow = qt * 64 + wave * 16 + l16;
    const unsigned short* qp = qb + ((long)(b * T_ + qrow)) * HS_;
    short8 aq0 = *(const short8*)&qp[0  + quad * 8];
    short8 aq1 = *(const short8*)&qp[32 + quad * 8];

    floatx4 acc_o[4] = { {0,0,0,0},{0,0,0,0},{0,0,0,0},{0,0,0,0} };
    float m_r[4] = { -INFINITY, -INFINITY, -INFINITY, -INFINITY };
    float l_r[4] = { 0.f, 0.f, 0.f, 0.f };

    const int rowg = qt * 64 + wave * 16 + quad * 4;

    const int skey = tid >> 3;
    const int sf8  = (tid & 7) * 8;
    const int vp = tid & 31, vg = tid >> 5;

    for (int c = s; c <= qt; c += NS) {
        const int kc = c * 64;
        #pragma unroll
        for (int it = 0; it < 2; ++it) {
            int key = it * 32 + skey;
            *(short8*)&Klds[key * LP + sf8] =
                *(const short8*)&kb[((long)(b * T_ + kc + key)) * HS_ + sf8];
        }
        {
            const unsigned short* v0p = &vb[((long)(b * T_ + kc + 2 * vp)) * HS_ + vg * 8];
            short8 v0 = *(const short8*)v0p;
            short8 v1 = *(const short8*)(v0p + HS_);
            #pragma unroll
            for (int j = 0; j < 8; ++j) {
                unsigned pr = (unsigned)(unsigned short)v0[j] |
                              ((unsigned)(unsigned short)v1[j] << 16);
                *(unsigned*)&Vt[(vg * 8 + j) * LP + 2 * vp] = pr;
            }
        }
        __syncthreads();

        floatx4 sv[4];
        #pragma unroll
        for (int kt = 0; kt < 4; ++kt) {
            floatx4 a = {0.f, 0.f, 0.f, 0.f};
            short8 bk0 = *(short8*)&Klds[(kt * 16 + l16) * LP + 0  + quad * 8];
            short8 bk1 = *(short8*)&Klds[(kt * 16 + l16) * LP + 32 + quad * 8];
            a = __builtin_amdgcn_mfma_f32_16x16x32_bf16(aq0, bk0, a, 0, 0, 0);
            a = __builtin_amdgcn_mfma_f32_16x16x32_bf16(aq1, bk1, a, 0, 0, 0);
            sv[kt] = a;
        }

        const bool lastc = (c == qt);
        #pragma unroll
        for (int kt = 0; kt < 4; ++kt) {
            int key = kc + kt * 16 + l16;
            int mk = mask[b * T_ + key];
            #pragma unroll
            for (int r = 0; r < 4; ++r) {
                bool dead = (mk == 0) || (lastc && key > rowg + r);
                if (dead) sv[kt][r] = -INFINITY;
            }
        }

        float alpha[4];
        #pragma unroll
        for (int r = 0; r < 4; ++r) {
            float mx = fmaxf(fmaxf(sv[0][r], sv[1][r]), fmaxf(sv[2][r], sv[3][r]));
            #pragma unroll
            for (int off = 1; off < 16; off <<= 1)
                mx = fmaxf(mx, __shfl_xor(mx, off));
            float mn = fmaxf(m_r[r], mx);
            float a_ = __expf(m_r[r] - mn);
            float ps = 0.f;
            #pragma unroll
            for (int kt = 0; kt < 4; ++kt) {
                float pv = __expf(sv[kt][r] - mn);
                sv[kt][r] = pv;
                ps += pv;
            }
            #pragma unroll
            for (int off = 1; off < 16; off <<= 1)
                ps += __shfl_xor(ps, off);
            l_r[r] = l_r[r] * a_ + ps;
            m_r[r] = mn;
            alpha[r] = a_;
        }
        #pragma unroll
        for (int nt = 0; nt < 4; ++nt)
            #pragma unroll
            for (int r = 0; r < 4; ++r)
                acc_o[nt][r] *= alpha[r];

        unsigned short* pl = Plds[wave];
        #pragma unroll
        for (int kt = 0; kt < 4; ++kt)
            #pragma unroll
            for (int r = 0; r < 4; ++r)
                pl[(quad * 4 + r) * LP + kt * 16 + l16] = f2bf(sv[kt][r]);
        short8 ap0 = *(short8*)&pl[l16 * LP + 0  + quad * 8];
        short8 ap1 = *(short8*)&pl[l16 * LP + 32 + quad * 8];

        #pragma unroll
        for (int nt = 0; nt < 4; ++nt) {
            short8 bv0 = *(short8*)&Vt[(nt * 16 + l16) * LP + 0  + quad * 8];
            short8 bv1 = *(short8*)&Vt[(nt * 16 + l16) * LP + 32 + quad * 8];
            acc_o[nt] = __builtin_amdgcn_mfma_f32_16x16x32_bf16(ap0, bv0, acc_o[nt], 0, 0, 0);
            acc_o[nt] = __builtin_amdgcn_mfma_f32_16x16x32_bf16(ap1, bv1, acc_o[nt], 0, 0, 0);
        }
        __syncthreads();
    }

    // write partials: O unnormalized (bf16), m/l fp32
    unsigned short* Op = Opart + (long)blockIdx.x * 4096;
    #pragma unroll
    for (int nt = 0; nt < 4; ++nt)
        #pragma unroll
        for (int r = 0; r < 4; ++r)
            Op[(wave * 16 + quad * 4 + r) * 64 + nt * 16 + l16] = f2bf(acc_o[nt][r]);
    if (l16 == 0) {
        #pragma unroll
        for (int r = 0; r < 4; ++r) {
            int rl = wave * 16 + quad * 4 + r;
            Mpart[(long)blockIdx.x * 64 + rl] = m_r[r];
            Lpart[(long)blockIdx.x * 64 + rl] = l_r[r];
        }
    }
}

// ---------------------------------------------------------------------------
// Kernel 3b: combine split partials. grid = 8b x 32qt x 2 = 512, block = 256.
// ---------------------------------------------------------------------------
__global__ __launch_bounds__(256) void attn_combine(
    const unsigned short* __restrict__ Opart, const float* __restrict__ Mpart,
    const float* __restrict__ Lpart, float* __restrict__ out)
{
    const int half = blockIdx.x & 1;
    const int bq = blockIdx.x >> 1;
    const int qt = bq & 31;
    const int b  = bq >> 5;
    const int nsp = (qt + 1 < NS) ? qt + 1 : NS;

    const int row  = (threadIdx.x >> 3) + half * 32;   // 0..63
    const int colg = (threadIdx.x & 7) * 8;
    const long base = (long)bq * NS;

    float M = -INFINITY;
    #pragma unroll
    for (int sp = 0; sp < NS; ++sp)
        if (sp < nsp) M = fmaxf(M, Mpart[(base + sp) * 64 + row]);

    float w[NS];
    float L = 0.f;
    #pragma unroll
    for (int sp = 0; sp < NS; ++sp)
        if (sp < nsp) {
            float e = __expf(Mpart[(base + sp) * 64 + row] - M);
            w[sp] = e;
            L += e * Lpart[(base + sp) * 64 + row];
        }

    float acc[8] = {0,0,0,0,0,0,0,0};
    #pragma unroll
    for (int sp = 0; sp < NS; ++sp)
        if (sp < nsp) {
            const unsigned short* Op = Opart + (base + sp) * 4096 + row * 64 + colg;
            short8 o = *(const short8*)Op;
            float ws = w[sp];
            #pragma unroll
            for (int j = 0; j < 8; ++j)
                acc[j] += ws * bf2f((unsigned short)o[j]);
        }

    float inv = 1.0f / L;
    float* op = out + ((long)(b * T_ + qt * 64 + row)) * HS_ + colg;
    floatx4 o0 = { acc[0] * inv, acc[1] * inv, acc[2] * inv, acc[3] * inv };
    floatx4 o1 = { acc[4] * inv, acc[5] * inv, acc[6] * inv, acc[7] * inv };
    *(floatx4*)op = o0;
    *(floatx4*)(op + 4) = o1;
}

// ---------------------------------------------------------------------------
extern "C" void kernel_launch(void* const* d_in, const int* in_sizes, int n_in,
                              void* d_out, int out_size, void* d_ws, size_t ws_size,
                              hipStream_t stream)
{
    const float* qv = (const float*)d_in[0];
    const float* kv = (const float*)d_in[1];
    const float* vv = (const float*)d_in[2];
    const int*   mask = (const int*)d_in[3];
    const float* Wq = (const float*)d_in[4];
    const float* Wk = (const float*)d_in[5];
    const float* Wv = (const float*)d_in[6];
    float* out = (float*)d_out;

    // ws layout: W^T x3 | q/k/v bf16 | O partials bf16 | M,L fp32  (~24.2 MB)
    unsigned short* wt    = (unsigned short*)d_ws;
    unsigned short* qbuf  = wt + 3 * C_ * HS_;
    unsigned short* kbuf  = qbuf + (long)B_ * T_ * HS_;
    unsigned short* vbuf  = kbuf + (long)B_ * T_ * HS_;
    unsigned short* Opart = vbuf + (long)B_ * T_ * HS_;
    float* Mpart = (float*)(Opart + (long)B_ * 32 * NS * 4096);
    float* Lpart = Mpart + (long)B_ * 32 * NS * 64;

    prep_wt<<<48, 256, 0, stream>>>(Wq, Wk, Wv, wt);
    proj_kernel<<<768, 256, 0, stream>>>(qv, kv, vv, wt, qbuf, kbuf, vbuf);
    attn_partial<<<B_ * 32 * NS, 256, 0, stream>>>(qbuf, kbuf, vbuf, mask, Opart, Mpart, Lpart);
    attn_combine<<<B_ * 32 * 2, 256, 0, stream>>>(Opart, Mpart, Lpart, out);
}